// Round 8
// baseline (492.960 us; speedup 1.0000x reference)
//
#include <hip/hip_runtime.h>
#include <hip/hip_bf16.h>
#include <math.h>

// Problem constants
#define NB    2
#define NSEQ  512
#define DIN   1024
#define DCOND 128
#define NF    8
#define NH    16
#define HD    64
constexpr float LN_EPS = 1e-5f;

// d_ws layout (bytes):
//   cond : 8*1024 f32                     32 KB   @ 0
//   Ahi  : (16,512,1024) bf16          16.78 MB   @ 32768
//   Alo  : same                                  @ 16809984
//   Bhi  : (2048,1024) bf16             4.19 MB   @ 33587200
//   Blo  : same                                  @ 37781504
//   Qh   : (256,512,64) bf16           16.78 MB   @ 41975808
//   Ql   : same                                  @ 58753024
//   Kh   : same                                  @ 75530240
//   Kl   : same                                  @ 92307456
// total ~109.1 MB
#define WS_COND 0
#define WS_AHI  32768
#define WS_ALO  16809984
#define WS_BHI  33587200
#define WS_BLO  37781504
#define WS_QH   41975808
#define WS_QL   58753024
#define WS_KH   75530240
#define WS_KL   92307456

using bf16x8 = __attribute__((ext_vector_type(8))) short;
using f32x4  = __attribute__((ext_vector_type(4))) float;

__device__ __forceinline__ unsigned short f2bf(float x) {
    unsigned int u = __float_as_uint(x);
    unsigned int r = (u + 0x7fffu + ((u >> 16) & 1u)) >> 16;   // RNE
    return (unsigned short)r;
}
__device__ __forceinline__ float bf2f(unsigned short h) {
    return __uint_as_float(((unsigned int)h) << 16);
}

__device__ __forceinline__ void gload16(const void* g, void* l) {
    __builtin_amdgcn_global_load_lds(
        (__attribute__((address_space(1))) void*)(const_cast<void*>(g)),
        (__attribute__((address_space(3))) void*)l, 16, 0, 0);
}

// ---------------------------------------------------------------------------
// Kernel A: cond[f,:] = LayerNorm((w_c @ code)[:,f]) * gamma + beta
// ---------------------------------------------------------------------------
__global__ __launch_bounds__(256)
void cond_kernel(const float* __restrict__ w_c, const float* __restrict__ code,
                 const float* __restrict__ gamma, const float* __restrict__ beta,
                 float* __restrict__ cond)
{
    __shared__ float sc[DCOND];
    __shared__ float rs[256], rs2[256];
    const int f = blockIdx.x;
    const int t = threadIdx.x;

    if (t < DCOND) sc[t] = code[t * NF + f];
    __syncthreads();

    float hv[4];
    float s = 0.f, s2 = 0.f;
#pragma unroll
    for (int r = 0; r < 4; ++r) {
        const int d = r * 256 + t;
        const float* row = w_c + (size_t)d * DCOND;
        float acc = 0.f;
#pragma unroll 8
        for (int c = 0; c < DCOND; c += 4) {
            float4 wv = *(const float4*)(row + c);
            float4 cv = *(const float4*)(sc + c);
            acc += wv.x * cv.x + wv.y * cv.y + wv.z * cv.z + wv.w * cv.w;
        }
        hv[r] = acc; s += acc; s2 += acc * acc;
    }
    rs[t] = s; rs2[t] = s2;
    __syncthreads();
    for (int off = 128; off > 0; off >>= 1) {
        if (t < off) { rs[t] += rs[t + off]; rs2[t] += rs2[t + off]; }
        __syncthreads();
    }
    const float mu  = rs[0] * (1.f / DIN);
    const float var = rs2[0] * (1.f / DIN) - mu * mu;
    const float rstd = rsqrtf(var + LN_EPS);
#pragma unroll
    for (int r = 0; r < 4; ++r) {
        const int d = r * 256 + t;
        cond[f * DIN + d] = (hv[r] - mu) * rstd * gamma[d] + beta[d];
    }
}

// ---------------------------------------------------------------------------
// Kernel B1: split modx = x * cond -> Ahi/Alo bf16, layout [bf][n][d].
// x read ONCE per element; loop over all 8 f per thread (cond in LDS).
// grid = 512 blocks x 256 thr (thread = (b,n,dgroup))
// ---------------------------------------------------------------------------
__global__ __launch_bounds__(256)
void split_x_kernel(const float* __restrict__ x, const float* __restrict__ cond,
                    short* __restrict__ Ahi, short* __restrict__ Alo)
{
    __shared__ float sc[NF * DIN];   // 32 KB
    const int t = threadIdx.x;
#pragma unroll
    for (int i = 0; i < 8; ++i)
        *(float4*)(sc + i * 1024 + t * 4) = *(const float4*)(cond + i * 1024 + t * 4);
    __syncthreads();

    const unsigned gid = blockIdx.x * 256 + t;   // < 131072
    const int dg = gid & 127;
    const int n  = (gid >> 7) & 511;
    const int b  = gid >> 16;

    const float* xs = x + ((size_t)b * NSEQ + n) * DIN + dg * 8;
    float4 x0 = *(const float4*)xs, x1 = *(const float4*)(xs + 4);
    float xv[8] = {x0.x, x0.y, x0.z, x0.w, x1.x, x1.y, x1.z, x1.w};

#pragma unroll
    for (int f = 0; f < 8; ++f) {
        const float* cs = sc + f * DIN + dg * 8;
        float4 c0 = *(const float4*)cs, c1 = *(const float4*)(cs + 4);
        float cv[8] = {c0.x, c0.y, c0.z, c0.w, c1.x, c1.y, c1.z, c1.w};
        bf16x8 hi, lo;
#pragma unroll
        for (int i = 0; i < 8; ++i) {
            float m = xv[i] * cv[i];
            unsigned short h = f2bf(m);
            hi[i] = (short)h;
            lo[i] = (short)f2bf(m - bf2f(h));
        }
        const size_t off = (size_t)(b * 8 + f) * 524288 + n * 1024 + dg * 8;
        *(bf16x8*)(Ahi + off) = hi;
        *(bf16x8*)(Alo + off) = lo;
    }
}

// ---------------------------------------------------------------------------
// Kernel B2: split W rows 0..2047 -> Bhi/Blo bf16
// ---------------------------------------------------------------------------
__global__ __launch_bounds__(256)
void split_w_kernel(const float* __restrict__ W,
                    short* __restrict__ Bhi, short* __restrict__ Blo)
{
    const unsigned idx = blockIdx.x * 256 + threadIdx.x;   // < 262144
    const float* ws = W + (size_t)idx * 8;
    float4 w0 = *(const float4*)ws, w1 = *(const float4*)(ws + 4);
    float m[8] = { w0.x, w0.y, w0.z, w0.w, w1.x, w1.y, w1.z, w1.w };
    bf16x8 hi, lo;
#pragma unroll
    for (int i = 0; i < 8; ++i) {
        unsigned short h = f2bf(m[i]);
        hi[i] = (short)h;
        lo[i] = (short)f2bf(m[i] - bf2f(h));
    }
    *(bf16x8*)(Bhi + (size_t)idx * 8) = hi;
    *(bf16x8*)(Blo + (size_t)idx * 8) = lo;
}

// ---------------------------------------------------------------------------
// Kernel C: bf16x3 MFMA projection (validated core).
// Epilogue now emits Qh/Ql/Kh/Kl bf16 (RTZ hi + RTZ residual), layout
// [bf*16+h][n][dd] -- same value chain as R7's split-at-scores (bit-identical).
// ---------------------------------------------------------------------------
__global__ __launch_bounds__(256, 2)
void proj_mfma_kernel(const short* __restrict__ Ahi_g, const short* __restrict__ Alo_g,
                      const short* __restrict__ Bhi_g, const short* __restrict__ Blo_g,
                      const float* __restrict__ bias,
                      short* __restrict__ Qh, short* __restrict__ Ql,
                      short* __restrict__ Kh, short* __restrict__ Kl)
{
    __shared__ short sAhi[128 * 32];
    __shared__ short sAlo[128 * 32];
    __shared__ short sBhi[128 * 32];
    __shared__ short sBlo[128 * 32];

    const int bf   = blockIdx.z;
    const int n0   = blockIdx.y * 128;
    const int bcol = blockIdx.x * 128;
    const int t    = threadIdx.x;
    const int w    = t >> 6, lane = t & 63;
    const int wr   = w >> 1, wc = w & 1;

    const int rl = lane >> 2;
    const int sl = (lane & 3) ^ ((lane >> 3) & 3);
    const size_t aoff = ((size_t)bf * NSEQ + n0 + 32 * w + rl) * DIN + sl * 8;
    const size_t boff = ((size_t)(bcol + 32 * w + rl)) * DIN + sl * 8;
    const short* gAh = Ahi_g + aoff;
    const short* gAl = Alo_g + aoff;
    const short* gBh = Bhi_g + boff;
    const short* gBl = Blo_g + boff;
    short* dAh = sAhi + 1024 * w;
    short* dAl = sAlo + 1024 * w;
    short* dBh = sBhi + 1024 * w;
    short* dBl = sBlo + 1024 * w;

    int offA[4], offB[4];
    const int g = lane >> 4;
#pragma unroll
    for (int fi = 0; fi < 4; ++fi) {
        int r  = wr * 64 + fi * 16 + (lane & 15);
        offA[fi] = r * 32 + ((g ^ ((r >> 1) & 3)) * 8);
        int rb = wc * 64 + fi * 16 + (lane & 15);
        offB[fi] = rb * 32 + ((g ^ ((rb >> 1) & 3)) * 8);
    }

    f32x4 acc[4][4];
#pragma unroll
    for (int i = 0; i < 4; ++i)
#pragma unroll
        for (int j = 0; j < 4; ++j) acc[i][j] = (f32x4){0.f, 0.f, 0.f, 0.f};

    for (int kb = 0; kb < DIN; kb += 32) {
        __syncthreads();
        gload16(gAh + kb, dAh);  gload16(gAh + kb + 16 * DIN, dAh + 512);
        gload16(gAl + kb, dAl);  gload16(gAl + kb + 16 * DIN, dAl + 512);
        gload16(gBh + kb, dBh);  gload16(gBh + kb + 16 * DIN, dBh + 512);
        gload16(gBl + kb, dBl);  gload16(gBl + kb + 16 * DIN, dBl + 512);
        __syncthreads();

        bf16x8 Ah[4], Al[4], Bh[4], Bl[4];
#pragma unroll
        for (int fi = 0; fi < 4; ++fi) {
            Ah[fi] = *(const bf16x8*)(sAhi + offA[fi]);
            Al[fi] = *(const bf16x8*)(sAlo + offA[fi]);
            Bh[fi] = *(const bf16x8*)(sBhi + offB[fi]);
            Bl[fi] = *(const bf16x8*)(sBlo + offB[fi]);
        }
#pragma unroll
        for (int i = 0; i < 4; ++i)
#pragma unroll
            for (int j = 0; j < 4; ++j) {
                acc[i][j] = __builtin_amdgcn_mfma_f32_16x16x32_bf16(Ah[i], Bh[j], acc[i][j], 0, 0, 0);
                acc[i][j] = __builtin_amdgcn_mfma_f32_16x16x32_bf16(Ah[i], Bl[j], acc[i][j], 0, 0, 0);
                acc[i][j] = __builtin_amdgcn_mfma_f32_16x16x32_bf16(Al[i], Bh[j], acc[i][j], 0, 0, 0);
            }
    }

    // epilogue: +bias, RTZ hi/lo split, scatter bf16 to Qh/Ql or Kh/Kl
#pragma unroll
    for (int j = 0; j < 4; ++j) {
        const int e = bcol + wc * 64 + j * 16 + (lane & 15);
        const float bv = bias[e];
        const int ek = e & 1023;
        const size_t base = ((size_t)(bf * NH + (ek >> 6)) * NSEQ) * HD + (ek & 63);
        short* dh = ((e < DIN) ? Qh : Kh) + base;
        short* dl = ((e < DIN) ? Ql : Kl) + base;
#pragma unroll
        for (int i = 0; i < 4; ++i) {
            const int rbase = n0 + wr * 64 + i * 16 + (lane >> 4) * 4;
            f32x4 v = acc[i][j];
#pragma unroll
            for (int rg = 0; rg < 4; ++rg) {
                const float u = v[rg] + bv;
                const unsigned uu = __float_as_uint(u);
                const float lo = u - __uint_as_float(uu & 0xffff0000u);
                dh[(size_t)(rbase + rg) * HD] = (short)(uu >> 16);
                dl[(size_t)(rbase + rg) * HD] = (short)(__float_as_uint(lo) >> 16);
            }
        }
    }
}

// ---------------------------------------------------------------------------
// Kernel D: MFMA scores + fused softmax, bf16 K staging, 2-phase prefetch.
// Swapped operands: D[m][n] = sum_d K[m][d] Q[n][d].
// K chunks (128 rows bf16 hi+lo) double-buffered in LDS via gload16,
// XOR-swizzled both sides (rule 21). STAGE(next) issued before compute(cur);
// one __syncthreads per chunk (drain doubles as buffer handoff).
// grid = (8 row-tiles, 256 bfh), 256 threads (4 waves x 16 q-rows).
// ---------------------------------------------------------------------------
__global__ __launch_bounds__(256, 2)
void scores_mfma_kernel(const short* __restrict__ Qh, const short* __restrict__ Ql,
                        const short* __restrict__ Kh, const short* __restrict__ Kl,
                        float* __restrict__ out)
{
    __shared__ short KhL[2][128 * 64];   // 2 x 16 KB
    __shared__ short KlL[2][128 * 64];   // 2 x 16 KB

    const int bfh = blockIdx.y;          // (b*8+f)*16+h
    const int rt  = blockIdx.x;
    const int t = threadIdx.x, w = t >> 6, lane = t & 63;
    const int g = lane >> 4, c16 = lane & 15;

    // ---- Q fragments: direct bf16 loads (lane's q-row) ----
    const size_t qoff = ((size_t)bfh * NSEQ + rt * 64 + 16 * w + c16) * HD;
    bf16x8 qh[2], ql[2];
#pragma unroll
    for (int ks = 0; ks < 2; ++ks) {
        qh[ks] = *(const bf16x8*)(Qh + qoff + ks * 32 + 8 * g);
        ql[ks] = *(const bf16x8*)(Ql + qoff + ks * 32 + 8 * g);
    }

    const short* Khg = Kh + (size_t)bfh * NSEQ * HD;
    const short* Klg = Kl + (size_t)bfh * NSEQ * HD;
    const int sr    = lane >> 3;                 // source row within 8-row group
    const int sslot = (lane & 7) ^ sr;           // inverse-swizzled 16B slot
    const int rsw   = c16 & 7;                   // read-side slot XOR (= row&7)

    f32x4 acc[32];
#pragma unroll
    for (int i = 0; i < 32; ++i) acc[i] = (f32x4){0.f, 0.f, 0.f, 0.f};

    // stage chunk c into buffer s: linear LDS dest, inverse-swz per-lane source
#define STAGE(s, c)                                                            \
    _Pragma("unroll")                                                          \
    for (int i = 0; i < 4; ++i) {                                              \
        const int r0 = 32 * w + 8 * i;                                         \
        gload16(Khg + ((size_t)((c) * 128 + r0 + sr)) * HD + sslot * 8,        \
                &KhL[s][r0 * 64]);                                             \
        gload16(Klg + ((size_t)((c) * 128 + r0 + sr)) * HD + sslot * 8,        \
                &KlL[s][r0 * 64]);                                             \
    }

    STAGE(0, 0)
    __syncthreads();                     // chunk 0 ready

#pragma unroll
    for (int c = 0; c < 4; ++c) {
        if (c < 3) STAGE((c + 1) & 1, c + 1)   // overlaps with compute below

#pragma unroll
        for (int mtl = 0; mtl < 8; ++mtl) {
            const int row = 16 * mtl + c16;
            const short* bh = &KhL[c & 1][row * 64];
            const short* bl = &KlL[c & 1][row * 64];
            f32x4 d = acc[c * 8 + mtl];
#pragma unroll
            for (int ks = 0; ks < 2; ++ks) {
                const int so = ((ks * 4 + g) ^ rsw) * 8;
                bf16x8 ah = *(const bf16x8*)(bh + so);
                bf16x8 al = *(const bf16x8*)(bl + so);
                d = __builtin_amdgcn_mfma_f32_16x16x32_bf16(ah, qh[ks], d, 0, 0, 0);
                d = __builtin_amdgcn_mfma_f32_16x16x32_bf16(ah, ql[ks], d, 0, 0, 0);
                d = __builtin_amdgcn_mfma_f32_16x16x32_bf16(al, qh[ks], d, 0, 0, 0);
            }
            acc[c * 8 + mtl] = d;
        }
        __syncthreads();                 // drains next-chunk loads + handoff
    }
#undef STAGE

    // ---- softmax over m (row n = rt*64 + 16w + c16) ----
    float m = -1e30f;
#pragma unroll
    for (int i = 0; i < 32; ++i)
#pragma unroll
        for (int r = 0; r < 4; ++r) m = fmaxf(m, acc[i][r]);
    m = fmaxf(m, __shfl_xor(m, 16));
    m = fmaxf(m, __shfl_xor(m, 32));

    float s = 0.f;
#pragma unroll
    for (int i = 0; i < 32; ++i)
#pragma unroll
        for (int r = 0; r < 4; ++r) {
            float e = __expf((acc[i][r] - m) * 0.125f);
            acc[i][r] = e;
            s += e;
        }
    s += __shfl_xor(s, 16);
    s += __shfl_xor(s, 32);
    const float inv = 1.f / s;

    // ---- store: 4 g-lanes of a row write one contiguous 64B line per i ----
    const int b = bfh >> 7, f = (bfh >> 4) & 7, h = bfh & 15;
    const int n = rt * 64 + 16 * w + c16;
    float* rowp = out + ((((size_t)(b * NH + h)) * NF + f) * NSEQ + n) * NSEQ;
#pragma unroll
    for (int i = 0; i < 32; ++i) {
        f32x4 v = acc[i] * inv;
        *(f32x4*)(rowp + 16 * i + 4 * g) = v;
    }
}

// ---------------------------------------------------------------------------
extern "C" void kernel_launch(void* const* d_in, const int* in_sizes, int n_in,
                              void* d_out, int out_size, void* d_ws, size_t ws_size,
                              hipStream_t stream)
{
    const float* x     = (const float*)d_in[0];
    const float* code  = (const float*)d_in[1];
    const float* w_c   = (const float*)d_in[2];
    const float* W     = (const float*)d_in[3];
    const float* bias  = (const float*)d_in[4];
    const float* gamma = (const float*)d_in[5];
    const float* beta  = (const float*)d_in[6];
    float* out = (float*)d_out;

    char* ws = (char*)d_ws;
    float* cond = (float*)(ws + WS_COND);
    short* Ahi  = (short*)(ws + WS_AHI);
    short* Alo  = (short*)(ws + WS_ALO);
    short* Bhi  = (short*)(ws + WS_BHI);
    short* Blo  = (short*)(ws + WS_BLO);
    short* Qh   = (short*)(ws + WS_QH);
    short* Ql   = (short*)(ws + WS_QL);
    short* Kh   = (short*)(ws + WS_KH);
    short* Kl   = (short*)(ws + WS_KL);

    cond_kernel<<<NF, 256, 0, stream>>>(w_c, code, gamma, beta, cond);
    split_x_kernel<<<512, 256, 0, stream>>>(x, cond, Ahi, Alo);
    split_w_kernel<<<1024, 256, 0, stream>>>(W, Bhi, Blo);

    dim3 gP(16, 4, NB * NF);
    proj_mfma_kernel<<<gP, 256, 0, stream>>>(Ahi, Alo, Bhi, Blo, bias, Qh, Ql, Kh, Kl);

    dim3 gS(8, NB * NF * NH);
    scores_mfma_kernel<<<gS, 256, 0, stream>>>(Qh, Ql, Kh, Kl, out);
}